// Round 13
// baseline (214.079 us; speedup 1.0000x reference)
//
#include <hip/hip_runtime.h>
#include <hip/hip_bf16.h>

// Problem constants (B,T,C,HS) = (8,4096,1024,64)
#define BB 8
#define TT 4096
#define CC 1024
#define HS 64

typedef __attribute__((ext_vector_type(8))) __bf16 bf16x8;
typedef __attribute__((ext_vector_type(4))) __bf16 bf16x4;
typedef __attribute__((ext_vector_type(4))) float f32x4;

static __device__ __forceinline__ unsigned pack_bf16(float a, float b) {
    unsigned short ua = __builtin_bit_cast(unsigned short, (__bf16)a);
    unsigned short ub = __builtin_bit_cast(unsigned short, (__bf16)b);
    return (unsigned)ua | ((unsigned)ub << 16);
}
static __device__ __forceinline__ unsigned pack_f16(float a, float b) {
    unsigned short ua = __builtin_bit_cast(unsigned short, (_Float16)a);
    unsigned short ub = __builtin_bit_cast(unsigned short, (_Float16)b);
    return (unsigned)ua | ((unsigned)ub << 16);
}
static __device__ __forceinline__ float h2f(unsigned short u) {
    return (float)__builtin_bit_cast(_Float16, u);
}

// ---------------------------------------------------------------------------
// Kernel 0: W prep.  Wt[192][1024] bf16 = [Wq^T * 0.125*log2(e) | Wk^T | Wv^T]
// ---------------------------------------------------------------------------
__global__ __launch_bounds__(256) void wprep_kernel(
    const float* __restrict__ Wq, const float* __restrict__ Wk,
    const float* __restrict__ Wv, __bf16* __restrict__ Wt)
{
    int i = blockIdx.x * 256 + threadIdx.x;
    int dr = i >> 10;
    int c  = i & 1023;
    int m  = dr >> 6;
    int d  = dr & 63;
    const float* src = (m == 0) ? Wq : ((m == 1) ? Wk : Wv);
    float v = src[(long)c * HS + d];
    if (m == 0) v *= 0.125f * 1.4426950408889634f;   // scale * log2e into Wq
    Wt[i] = (__bf16)v;
}

// ---------------------------------------------------------------------------
// Kernel 1: QKV projection + RoPE.  One block = 64 token rows, 4 waves x 16.
// Q,K stored row-major [t][d]; V stored TRANSPOSED Vt[b*64+d][t] (via LDS).
// ---------------------------------------------------------------------------
__global__ __launch_bounds__(256) void qkv_rope_kernel(
    const float* __restrict__ x,     // [B*T][C]
    const float* __restrict__ cosT,  // [T][32]
    const float* __restrict__ sinT,  // [T][32]
    const __bf16* __restrict__ Wt,   // [192][1024]
    __bf16* __restrict__ Qo, __bf16* __restrict__ Ko, __bf16* __restrict__ Vo)
{
    __shared__ __bf16 xs[64][72];
    __shared__ __bf16 Wl[192][72];

    const int tid  = threadIdx.x;
    const int lane = tid & 63;
    const int w    = tid >> 6;
    const int col  = lane & 15;
    const int grp  = lane >> 4;
    const long rowbase = (long)blockIdx.x * 64;

    f32x4 acc[12];
#pragma unroll
    for (int i = 0; i < 12; i++) acc[i] = 0.0f;

    for (int ck = 0; ck < CC; ck += 64) {
        {
            int r = tid >> 2, c0 = (tid & 3) * 16;
            const float4* src = (const float4*)(x + (rowbase + r) * (long)CC + ck + c0);
#pragma unroll
            for (int i = 0; i < 4; i++) {
                float4 v = src[i];
                bf16x4 t;
                t[0] = (__bf16)v.x; t[1] = (__bf16)v.y;
                t[2] = (__bf16)v.z; t[3] = (__bf16)v.w;
                *(bf16x4*)&xs[r][c0 + i * 4] = t;
            }
        }
        {
#pragma unroll
            for (int i = 0; i < 6; i++) {
                int u = i * 256 + tid;
                int dr = u >> 3, cu = (u & 7) * 8;
                bf16x8 v = *(const bf16x8*)(Wt + (long)dr * CC + ck + cu);
                *(bf16x8*)&Wl[dr][cu] = v;
            }
        }
        __syncthreads();
#pragma unroll
        for (int s = 0; s < 2; s++) {
            bf16x8 a = *(const bf16x8*)&xs[w * 16 + col][s * 32 + grp * 8];
#pragma unroll
            for (int nf = 0; nf < 12; nf++) {
                bf16x8 b = *(const bf16x8*)&Wl[nf * 16 + col][s * 32 + grp * 8];
                acc[nf] = __builtin_amdgcn_mfma_f32_16x16x32_bf16(a, b, acc[nf], 0, 0, 0);
            }
        }
        __syncthreads();
    }

#pragma unroll
    for (int r = 0; r < 4; r++) {
        long grow = rowbase + w * 16 + grp * 4 + r;
        int t = (int)(grow & (TT - 1));
        const float* cp = cosT + (long)t * 32;
        const float* sp = sinT + (long)t * 32;
#pragma unroll
        for (int nf = 0; nf < 4; nf++) {
            int ii = nf * 8 + (col >> 1);
            float cs = cp[ii], sn = sp[ii];
            float sgn_sn = (col & 1) ? sn : -sn;
            float qv = acc[nf][r];
            float qp = __shfl_xor(qv, 1);
            float qo = qv * cs + qp * sgn_sn;
            float kv = acc[nf + 4][r];
            float kp = __shfl_xor(kv, 1);
            float ko = kv * cs + kp * sgn_sn;
            long base = grow * HS + nf * 16 + col;
            Qo[base] = (__bf16)qo;
            Ko[base] = (__bf16)ko;
            xs[nf * 16 + col][w * 16 + grp * 4 + r] = (__bf16)acc[nf + 8][r];
        }
    }
    __syncthreads();
    {
        int d = tid >> 2, seg = tid & 3;
        int b  = (int)(rowbase >> 12);
        int t0 = (int)(rowbase & (TT - 1));
        bf16x8 v0 = *(const bf16x8*)&xs[d][seg * 16];
        bf16x8 v1 = *(const bf16x8*)&xs[d][seg * 16 + 8];
        __bf16* dst = Vo + ((size_t)b * 64 + d) * TT + t0 + seg * 16;
        *(bf16x8*)dst = v0;
        *(bf16x8*)(dst + 8) = v1;
    }
}

// ---------------------------------------------------------------------------
// Kernel 2: causal flash attention.  K/V LDS-shared (reg-staged, swizzled),
// K 2-buf, V 2-buf + V-frag prefetch one iter early (registers carry V across
// the barrier so writes never race reads).  T15 two-tile pipeline, ONE
// barrier per tile.  4 blocks/CU (40KB LDS).
// Grid 1024: b=n&7, k=n>>3 in 0..127:
//   k<64 : qt=63-k, ch0 = kv tiles [0, ceil((qt+1)/2))      (heavy first)
//   else : qt=k-64, ch1 = kv tiles [ceil((qt+1)/2), qt+1)
// CU c hosts k0,k0+32,k0+64,k0+96 -> 64-66 tiles always.
// All blocks write l-normalized f16 partials + (m,l); combine merges 2 chunks.
// ---------------------------------------------------------------------------
__global__ __launch_bounds__(256, 4) void attn_kernel(
    const __bf16* __restrict__ Q, const __bf16* __restrict__ K,
    const __bf16* __restrict__ Vt,
    _Float16* __restrict__ Opart, float* __restrict__ mlbuf)
{
    __shared__ __bf16 Kl[2][64 * 64];                  // swizzled image, 8KB each
    __shared__ __bf16 Vl[2][64 * 64];
    __shared__ __align__(16) unsigned char plds[4][2048];

    const int tid  = threadIdx.x;
    const int lane = tid & 63;
    const int col  = lane & 15;
    const int g    = lane >> 4;
    const int w    = tid >> 6;

    const int n = blockIdx.x;
    const int b = n & 7;
    const int k = n >> 3;
    int qt, ch, j0, j1;
    if (k < 64) { qt = 63 - k; ch = 0; j0 = 0;             j1 = (qt + 2) >> 1; }
    else        { qt = k - 64; ch = 1; j0 = (qt + 2) >> 1; j1 = qt + 1; }

    const size_t slot = (size_t)(b * 64 + qt) * 2 + ch;
    const int rowg = w * 16 + col;

    if (j0 >= j1) {                                    // empty chunk (qt=0,ch1)
        _Float16* prow = Opart + slot * 4096 + (size_t)rowg * 64;
        uint2 z; z.x = 0u; z.y = 0u;
#pragma unroll
        for (int nf = 0; nf < 4; nf++)
            *(uint2*)(prow + nf * 16 + g * 4) = z;
        if (g == 0) {
            float2 mv = make_float2(-3e38f, 0.f);
            *(float2*)(mlbuf + (slot * 64 + rowg) * 2) = mv;
        }
        return;
    }

    const int qloc = qt * 64 + rowg;                   // lane's q row in sequence
    const size_t qrow = (size_t)b * TT + qloc;
    bf16x8 qb[2];
#pragma unroll
    for (int s = 0; s < 2; s++)
        qb[s] = *(const bf16x8*)(Q + qrow * HS + s * 32 + g * 8);

    // stage-thread geometry: thread handles 16B chunks (r0,c0),(r1,c0)
    const int r0 = tid >> 3, c0 = tid & 7;
    const int r1 = r0 + 32;
    const __bf16* Kbase = K + (size_t)b * TT * HS;
    const __bf16* Vbase = Vt + (size_t)b * 64 * TT;

#define SWZ(row, cb) (((row) << 6) | (((cb) ^ ((row) & 7)) << 3))

    f32x4 acc[4];
#pragma unroll
    for (int i = 0; i < 4; i++) acc[i] = 0.f;
    float mrun = -3e38f;
    float lsum0 = 0.f, lsum1 = 0.f, lsum2 = 0.f, lsum3 = 0.f;

    unsigned char* pbase = plds[w] + col * 128;
    const int sw = col & 7;

    bf16x8 sk0, sk1, sv0, sv1;                          // staging registers
    auto stageLoad = [&](int j) {
        const __bf16* kp = Kbase + (size_t)(j * 64) * HS;
        sk0 = *(const bf16x8*)(kp + r0 * HS + c0 * 8);
        sk1 = *(const bf16x8*)(kp + r1 * HS + c0 * 8);
        const __bf16* vp = Vbase + j * 64;
        sv0 = *(const bf16x8*)(vp + (size_t)r0 * TT + c0 * 8);
        sv1 = *(const bf16x8*)(vp + (size_t)r1 * TT + c0 * 8);
    };
    auto stageWrite = [&](int buf) {
        *(bf16x8*)&Kl[buf][SWZ(r0, c0)] = sk0;
        *(bf16x8*)&Kl[buf][SWZ(r1, c0)] = sk1;
        *(bf16x8*)&Vl[buf][SWZ(r0, c0)] = sv0;
        *(bf16x8*)&Vl[buf][SWZ(r1, c0)] = sv1;
    };
    // read V fragments of LDS buffer vb into registers (prefetch for next iter)
    auto loadVfrag = [&](int vb, bf16x8 (&vf)[8]) {
#pragma unroll
        for (int nf = 0; nf < 4; nf++)
#pragma unroll
            for (int s = 0; s < 2; s++)
                vf[nf * 2 + s] = *(const bf16x8*)&Vl[vb][SWZ(nf * 16 + col, s * 4 + g)];
    };

    f32x4 sfA[4], sfB[4];
    bf16x8 vfA[8], vfB[8];

    // QK phase: S^T(tile jv) from Kl[jv&1] into SF (no consumer this iter)
    auto qkPhase = [&](int jv, f32x4 (&SF)[4]) {
        bf16x8 kf[8];
#pragma unroll
        for (int nf = 0; nf < 4; nf++)
#pragma unroll
            for (int s = 0; s < 2; s++)
                kf[nf * 2 + s] = *(const bf16x8*)&Kl[jv & 1][SWZ(nf * 16 + col, s * 4 + g)];
        __builtin_amdgcn_s_setprio(1);
#pragma unroll
        for (int s = 0; s < 2; s++)
#pragma unroll
            for (int nf = 0; nf < 4; nf++)
                SF[nf] = __builtin_amdgcn_mfma_f32_16x16x32_bf16(kf[nf * 2 + s], qb[s], SF[nf], 0, 0, 0);
        __builtin_amdgcn_s_setprio(0);
    };

    // finish phase: softmax + PV of tile jv; V frags already in registers
    auto finPhase = [&](int jv, f32x4 (&SF)[4], bf16x8 (&vf)[8]) {
        if (jv == qt) {                                 // causal mask (diag only)
#pragma unroll
            for (int nf = 0; nf < 4; nf++)
#pragma unroll
                for (int r = 0; r < 4; r++)
                    if (jv * 64 + nf * 16 + g * 4 + r > qloc) SF[nf][r] = -3e38f;
        }
        float fm[4];
#pragma unroll
        for (int f = 0; f < 4; f++)
            fm[f] = fmaxf(fmaxf(SF[f][0], SF[f][1]), fmaxf(SF[f][2], SF[f][3]));
        float mt = fmaxf(fmaxf(fm[0], fm[1]), fmaxf(fm[2], fm[3]));
        if (!__all(mt <= mrun + 8.0f)) {                // defer-max (THR=8)
            float mg = fmaxf(mt, __shfl_xor(mt, 16));
            mg = fmaxf(mg, __shfl_xor(mg, 32));
            float mn = fmaxf(mrun, mg);
            float al = exp2f(mrun - mn);
            mrun = mn;
            lsum0 *= al; lsum1 *= al; lsum2 *= al; lsum3 *= al;
#pragma unroll
            for (int nf = 0; nf < 4; nf++) acc[nf] *= al;
        }
#pragma unroll
        for (int f = 0; f < 4; f++) {
            float p0 = exp2f(SF[f][0] - mrun);
            float p1 = exp2f(SF[f][1] - mrun);
            float p2 = exp2f(SF[f][2] - mrun);
            float p3 = exp2f(SF[f][3] - mrun);
            SF[f][0] = p0; SF[f][1] = p1; SF[f][2] = p2; SF[f][3] = p3;
            lsum0 += p0; lsum1 += p1; lsum2 += p2; lsum3 += p3;
        }
#pragma unroll
        for (int nf = 0; nf < 4; nf++) {                // P^T -> P rows (bounce)
            uint2 val;
            val.x = pack_bf16(SF[nf][0], SF[nf][1]);
            val.y = pack_bf16(SF[nf][2], SF[nf][3]);
            *(uint2*)(pbase + ((((nf * 2 + (g >> 1)) ^ sw) << 4) | ((g & 1) << 3))) = val;
        }
        __builtin_amdgcn_s_setprio(1);
#pragma unroll
        for (int s = 0; s < 2; s++) {
            bf16x8 pf = *(const bf16x8*)(pbase + (((s * 4 + g) ^ sw) << 4));
#pragma unroll
            for (int nf = 0; nf < 4; nf++)
                acc[nf] = __builtin_amdgcn_mfma_f32_16x16x32_bf16(vf[nf * 2 + s], pf, acc[nf], 0, 0, 0);
        }
        __builtin_amdgcn_s_setprio(0);
    };

    // one pipelined step: stage(jv+1), QK(jv), finish(jv-1) w/ vfF, prefetch vfN
    auto iterStep = [&](int jv, f32x4 (&SFq)[4], f32x4 (&SFf)[4],
                        bf16x8 (&vfF)[8], bf16x8 (&vfN)[8]) {
        const bool more = (jv + 1 < j1);
        if (more) stageLoad(jv + 1);
        __builtin_amdgcn_sched_barrier(0);              // pin loads above compute
#pragma unroll
        for (int i = 0; i < 4; i++) SFq[i] = 0.f;
        qkPhase(jv, SFq);
        finPhase(jv - 1, SFf, vfF);
        loadVfrag(jv & 1, vfN);                         // V(jv) for next finish
        if (more) stageWrite((jv + 1) & 1);             // != jv&1: no read race
        __syncthreads();
    };

    // ---- prologue: stage tile j0 into buffer j0&1 ----
    stageLoad(j0);
    stageWrite(j0 & 1);
    __syncthreads();

    // ---- iter0: QK(j0), prefetch V(j0) frags, stage j0+1 ----
    {
        const bool more = (j0 + 1 < j1);
        if (more) stageLoad(j0 + 1);
        __builtin_amdgcn_sched_barrier(0);
#pragma unroll
        for (int i = 0; i < 4; i++) sfA[i] = 0.f;
        qkPhase(j0, sfA);
        loadVfrag(j0 & 1, vfA);
        if (more) stageWrite((j0 + 1) & 1);
        __syncthreads();
    }

    int jv = j0 + 1;
    while (jv + 1 < j1) {
        iterStep(jv, sfB, sfA, vfA, vfB);
        iterStep(jv + 1, sfA, sfB, vfB, vfA);
        jv += 2;
    }
    bool lastIsB = false;
    if (jv < j1) {                                      // one leftover step
        iterStep(jv, sfB, sfA, vfA, vfB);
        lastIsB = true;
    }
    // ---- final finish of tile j1-1 ----
    if (lastIsB) finPhase(j1 - 1, sfB, vfB);
    else         finPhase(j1 - 1, sfA, vfA);

    // ---- epilogue: l-normalized f16 partial + (m,l) per row ----
    float ls = (lsum0 + lsum1) + (lsum2 + lsum3);
    ls += __shfl_xor(ls, 16);
    ls += __shfl_xor(ls, 32);
    float rinv = (ls > 0.f) ? __builtin_amdgcn_rcpf(ls) : 0.f;
    _Float16* prow = Opart + slot * 4096 + (size_t)rowg * 64;
#pragma unroll
    for (int nf = 0; nf < 4; nf++) {
        uint2 v;
        v.x = pack_f16(acc[nf][0] * rinv, acc[nf][1] * rinv);
        v.y = pack_f16(acc[nf][2] * rinv, acc[nf][3] * rinv);
        *(uint2*)(prow + nf * 16 + g * 4) = v;
    }
    if (g == 0) {
        float2 mv = make_float2(mrun, ls);
        *(float2*)(mlbuf + (slot * 64 + rowg) * 2) = mv;
    }
#undef SWZ
}

// ---------------------------------------------------------------------------
// Kernel 3: combine the two split-K partial chunks for every 64-row q-tile.
// ---------------------------------------------------------------------------
__global__ __launch_bounds__(256) void combine_kernel(
    const _Float16* __restrict__ Opart, const float* __restrict__ mlbuf,
    float* __restrict__ O)
{
    const int qt = blockIdx.x;             // 0..63
    const int b  = blockIdx.y;
    const int row = threadIdx.x >> 2;      // 0..63
    const int seg = threadIdx.x & 3;       // 16 dims each
    const size_t slot0 = (size_t)(b * 64 + qt) * 2;

    const float* p0 = mlbuf + ((slot0 + 0) * 64 + row) * 2;
    const float* p1 = mlbuf + ((slot0 + 1) * 64 + row) * 2;
    float m0 = p0[0], l0 = p0[1];
    float m1 = p1[0], l1 = p1[1];
    float M  = fmaxf(m0, m1);
    float w0 = l0 * exp2f(m0 - M);
    float w1 = l1 * exp2f(m1 - M);
    float rinv = 1.0f / (w0 + w1);
    w0 *= rinv; w1 *= rinv;

    const uint4* s0 = (const uint4*)(Opart + (slot0 + 0) * 4096 + (size_t)row * 64 + seg * 16);
    const uint4* s1 = (const uint4*)(Opart + (slot0 + 1) * 4096 + (size_t)row * 64 + seg * 16);
    float* dst = O + ((size_t)b * TT + qt * 64 + row) * 64 + seg * 16;
#pragma unroll
    for (int i = 0; i < 2; i++) {
        uint4 a = s0[i], c = s1[i];
        float4 v;
        v.x = h2f((unsigned short)(a.x      )) * w0 + h2f((unsigned short)(c.x      )) * w1;
        v.y = h2f((unsigned short)(a.x >> 16)) * w0 + h2f((unsigned short)(c.x >> 16)) * w1;
        v.z = h2f((unsigned short)(a.y      )) * w0 + h2f((unsigned short)(c.y      )) * w1;
        v.w = h2f((unsigned short)(a.y >> 16)) * w0 + h2f((unsigned short)(c.y >> 16)) * w1;
        *(float4*)(dst + i * 8) = v;
        float4 u;
        u.x = h2f((unsigned short)(a.z      )) * w0 + h2f((unsigned short)(c.z      )) * w1;
        u.y = h2f((unsigned short)(a.z >> 16)) * w0 + h2f((unsigned short)(c.z >> 16)) * w1;
        u.z = h2f((unsigned short)(a.w      )) * w0 + h2f((unsigned short)(c.w      )) * w1;
        u.w = h2f((unsigned short)(a.w >> 16)) * w0 + h2f((unsigned short)(c.w >> 16)) * w1;
        *(float4*)(dst + i * 8 + 4) = u;
    }
}

// ---------------------------------------------------------------------------
extern "C" void kernel_launch(void* const* d_in, const int* in_sizes, int n_in,
                              void* d_out, int out_size, void* d_ws, size_t ws_size,
                              hipStream_t stream)
{
    const float* x    = (const float*)d_in[0];
    const float* cosT = (const float*)d_in[1];
    const float* sinT = (const float*)d_in[2];
    const float* Wq   = (const float*)d_in[3];
    const float* Wk   = (const float*)d_in[4];
    const float* Wv   = (const float*)d_in[5];
    float* out = (float*)d_out;

    __bf16* Qb = (__bf16*)d_ws;
    __bf16* Kb = Qb + (size_t)BB * TT * HS;
    __bf16* Vb = Kb + (size_t)BB * TT * HS;   // transposed: [b*64+d][t]
    __bf16* Wt = Vb + (size_t)BB * TT * HS;

    const size_t base_bytes = (size_t)3 * BB * TT * HS * 2 + 192 * 1024 * 2;
    _Float16* Opart = (_Float16*)((char*)d_ws + ((base_bytes + 255) & ~(size_t)255));
    float* mlbuf = (float*)(Opart + (size_t)1024 * 4096);  // 8.39MB f16 partials

    wprep_kernel<<<(192 * 1024) / 256, 256, 0, stream>>>(Wq, Wk, Wv, Wt);
    qkv_rope_kernel<<<(BB * TT) / 64, 256, 0, stream>>>(x, cosT, sinT, Wt, Qb, Kb, Vb);
    attn_kernel<<<1024, 256, 0, stream>>>(Qb, Kb, Vb, Opart, mlbuf);
    combine_kernel<<<dim3(64, 8), 256, 0, stream>>>(Opart, mlbuf, out);
}

// Round 15
// 83.702 us; speedup vs baseline: 2.5576x; 2.5576x over previous
//
#include <hip/hip_runtime.h>
#include <hip/hip_bf16.h>

// Problem constants (B,T,C,HS) = (8,4096,1024,64)
#define BB 8
#define TT 4096
#define CC 1024
#define HS 64

typedef __attribute__((ext_vector_type(8))) __bf16 bf16x8;
typedef __attribute__((ext_vector_type(4))) __bf16 bf16x4;
typedef __attribute__((ext_vector_type(4))) float f32x4;
typedef __attribute__((ext_vector_type(2))) int int2v;
typedef __attribute__((ext_vector_type(4))) unsigned uint4v;

static __device__ __forceinline__ unsigned pack_bf16(float a, float b) {
    unsigned short ua = __builtin_bit_cast(unsigned short, (__bf16)a);
    unsigned short ub = __builtin_bit_cast(unsigned short, (__bf16)b);
    return (unsigned)ua | ((unsigned)ub << 16);
}

// ---------------------------------------------------------------------------
// Kernel 0: W prep.  Wt[192][1024] bf16 = [Wq^T * 0.125*log2(e) | Wk^T | Wv^T]
// ---------------------------------------------------------------------------
__global__ __launch_bounds__(256) void wprep_kernel(
    const float* __restrict__ Wq, const float* __restrict__ Wk,
    const float* __restrict__ Wv, __bf16* __restrict__ Wt)
{
    int i = blockIdx.x * 256 + threadIdx.x;
    int dr = i >> 10;
    int c  = i & 1023;
    int m  = dr >> 6;
    int d  = dr & 63;
    const float* src = (m == 0) ? Wq : ((m == 1) ? Wk : Wv);
    float v = src[(long)c * HS + d];
    if (m == 0) v *= 0.125f * 1.4426950408889634f;   // scale * log2e into Wq
    Wt[i] = (__bf16)v;
}

// ---------------------------------------------------------------------------
// Kernel 1: QKV projection + RoPE.  One block = 64 token rows, 4 waves x 16.
// Q,K stored row-major [t][d]; V stored TRANSPOSED Vt[b*64+d][t] (via LDS).
// ---------------------------------------------------------------------------
__global__ __launch_bounds__(256) void qkv_rope_kernel(
    const float* __restrict__ x,     // [B*T][C]
    const float* __restrict__ cosT,  // [T][32]
    const float* __restrict__ sinT,  // [T][32]
    const __bf16* __restrict__ Wt,   // [192][1024]
    __bf16* __restrict__ Qo, __bf16* __restrict__ Ko, __bf16* __restrict__ Vo)
{
    __shared__ __bf16 xs[64][72];
    __shared__ __bf16 Wl[192][72];

    const int tid  = threadIdx.x;
    const int lane = tid & 63;
    const int w    = tid >> 6;
    const int col  = lane & 15;
    const int grp  = lane >> 4;
    const long rowbase = (long)blockIdx.x * 64;

    f32x4 acc[12];
#pragma unroll
    for (int i = 0; i < 12; i++) acc[i] = 0.0f;

    for (int ck = 0; ck < CC; ck += 64) {
        {
            int r = tid >> 2, c0 = (tid & 3) * 16;
            const float4* src = (const float4*)(x + (rowbase + r) * (long)CC + ck + c0);
#pragma unroll
            for (int i = 0; i < 4; i++) {
                float4 v = src[i];
                bf16x4 t;
                t[0] = (__bf16)v.x; t[1] = (__bf16)v.y;
                t[2] = (__bf16)v.z; t[3] = (__bf16)v.w;
                *(bf16x4*)&xs[r][c0 + i * 4] = t;
            }
        }
        {
#pragma unroll
            for (int i = 0; i < 6; i++) {
                int u = i * 256 + tid;
                int dr = u >> 3, cu = (u & 7) * 8;
                bf16x8 v = *(const bf16x8*)(Wt + (long)dr * CC + ck + cu);
                *(bf16x8*)&Wl[dr][cu] = v;
            }
        }
        __syncthreads();
#pragma unroll
        for (int s = 0; s < 2; s++) {
            bf16x8 a = *(const bf16x8*)&xs[w * 16 + col][s * 32 + grp * 8];
#pragma unroll
            for (int nf = 0; nf < 12; nf++) {
                bf16x8 b = *(const bf16x8*)&Wl[nf * 16 + col][s * 32 + grp * 8];
                acc[nf] = __builtin_amdgcn_mfma_f32_16x16x32_bf16(a, b, acc[nf], 0, 0, 0);
            }
        }
        __syncthreads();
    }

#pragma unroll
    for (int r = 0; r < 4; r++) {
        long grow = rowbase + w * 16 + grp * 4 + r;
        int t = (int)(grow & (TT - 1));
        const float* cp = cosT + (long)t * 32;
        const float* sp = sinT + (long)t * 32;
#pragma unroll
        for (int nf = 0; nf < 4; nf++) {
            int ii = nf * 8 + (col >> 1);
            float cs = cp[ii], sn = sp[ii];
            float sgn_sn = (col & 1) ? sn : -sn;
            float qv = acc[nf][r];
            float qp = __shfl_xor(qv, 1);
            float qo = qv * cs + qp * sgn_sn;
            float kv = acc[nf + 4][r];
            float kp = __shfl_xor(kv, 1);
            float ko = kv * cs + kp * sgn_sn;
            long base = grow * HS + nf * 16 + col;
            Qo[base] = (__bf16)qo;
            Ko[base] = (__bf16)ko;
            xs[nf * 16 + col][w * 16 + grp * 4 + r] = (__bf16)acc[nf + 8][r];
        }
    }
    __syncthreads();
    {
        int d = tid >> 2, seg = tid & 3;
        int b  = (int)(rowbase >> 12);
        int t0 = (int)(rowbase & (TT - 1));
        bf16x8 v0 = *(const bf16x8*)&xs[d][seg * 16];
        bf16x8 v1 = *(const bf16x8*)&xs[d][seg * 16 + 8];
        __bf16* dst = Vo + ((size_t)b * 64 + d) * TT + t0 + seg * 16;
        *(bf16x8*)dst = v0;
        *(bf16x8*)(dst + 8) = v1;
    }
}

// ---------------------------------------------------------------------------
// Kernel 2: causal flash attention, LDS-shared K/V, split-K (R7 balance),
// T15 two-tile pipeline, P re-fragmentation fully IN-REGISTER via
// permlane32_swap + permlane16_swap (T12, corrected mapping):
//   p = pl32swap(d[2s], d[2s+1]) -> p.x=[Aq0,Aq1,Bq0,Bq1], p.y=[Aq2,Aq3,Bq2,Bq3]
//   u = pl16swap(p.x, p.y)       -> u.x=[Aq0,Aq2,Bq0,Bq2]=word_lo, u.y=word_hi
// K 2-buffered, V 3-buffered, ONE __syncthreads per tile.
// Block n: b=n&7, idx=n>>3 in 0..95:
//   idx<32 : qt=32+idx, tiles [0,32)      -> partial ch0   (32 tiles)
//   idx<64 : qt=idx,    tiles [32,qt]     -> partial ch1   (idx-31 tiles)
//   else   : qt=95-idx, tiles [0,qt]      -> direct write  (96-idx tiles)
// ---------------------------------------------------------------------------
__global__ __launch_bounds__(256, 3) void attn_kernel(
    const __bf16* __restrict__ Q, const __bf16* __restrict__ K,
    const __bf16* __restrict__ Vt, float* __restrict__ O,
    float* __restrict__ Opart, float* __restrict__ mlbuf)
{
    __shared__ __bf16 Kl[2][64 * 64];                  // swizzled, 8KB each
    __shared__ __bf16 Vl[3][64 * 64];                  // swizzled, 8KB each

    const int tid  = threadIdx.x;
    const int lane = tid & 63;
    const int col  = lane & 15;
    const int g    = lane >> 4;
    const int w    = tid >> 6;

    const int n   = blockIdx.x;
    const int b   = n & 7;
    const int idx = n >> 3;
    int qt, j0, j1, ch;
    bool partial;
    if (idx < 32)      { qt = 32 + idx;  j0 = 0;  j1 = 32;     partial = true;  ch = 0; }
    else if (idx < 64) { qt = idx;       j0 = 32; j1 = qt + 1; partial = true;  ch = 1; }
    else               { qt = 95 - idx;  j0 = 0;  j1 = qt + 1; partial = false; ch = 0; }

    const int qloc = qt * 64 + w * 16 + col;           // lane's q row in sequence
    const size_t qrow = (size_t)b * TT + qloc;
    bf16x8 qb[2];
#pragma unroll
    for (int s = 0; s < 2; s++)
        qb[s] = *(const bf16x8*)(Q + qrow * HS + s * 32 + g * 8);

    // stage-thread geometry: thread handles 16B chunks (r0,c0),(r1,c0)
    const int r0 = tid >> 3, c0 = tid & 7;
    const int r1 = r0 + 32;
    const __bf16* Kbase = K + (size_t)b * TT * HS;
    const __bf16* Vbase = Vt + (size_t)b * 64 * TT;

#define SWZ(row, cb) (((row) << 6) | (((cb) ^ ((row) & 7)) << 3))

    f32x4 acc[4];
#pragma unroll
    for (int i = 0; i < 4; i++) acc[i] = 0.f;
    float mrun = -3e38f;
    float lsum0 = 0.f, lsum1 = 0.f, lsum2 = 0.f, lsum3 = 0.f;

    bf16x8 sk0, sk1, sv0, sv1;                          // staging registers
    auto stageLoad = [&](int j) {
        const __bf16* kp = Kbase + (size_t)(j * 64) * HS;
        sk0 = *(const bf16x8*)(kp + r0 * HS + c0 * 8);
        sk1 = *(const bf16x8*)(kp + r1 * HS + c0 * 8);
        const __bf16* vp = Vbase + j * 64;
        sv0 = *(const bf16x8*)(vp + (size_t)r0 * TT + c0 * 8);
        sv1 = *(const bf16x8*)(vp + (size_t)r1 * TT + c0 * 8);
    };
    auto stageWriteK = [&](int kb) {
        *(bf16x8*)&Kl[kb][SWZ(r0, c0)] = sk0;
        *(bf16x8*)&Kl[kb][SWZ(r1, c0)] = sk1;
    };
    auto stageWriteV = [&](int vb) {
        *(bf16x8*)&Vl[vb][SWZ(r0, c0)] = sv0;
        *(bf16x8*)&Vl[vb][SWZ(r1, c0)] = sv1;
    };

    f32x4 sfA[4], sfB[4];

    // QK phase: S^T(tile jv) from Kl[jv&1] into SF (no consumer this iter)
    auto qkPhase = [&](int jv, f32x4 (&SF)[4]) {
        bf16x8 kf[8];
#pragma unroll
        for (int nf = 0; nf < 4; nf++)
#pragma unroll
            for (int s = 0; s < 2; s++)
                kf[nf * 2 + s] = *(const bf16x8*)&Kl[jv & 1][SWZ(nf * 16 + col, s * 4 + g)];
        __builtin_amdgcn_s_setprio(1);
#pragma unroll
        for (int s = 0; s < 2; s++)
#pragma unroll
            for (int nf = 0; nf < 4; nf++)
                SF[nf] = __builtin_amdgcn_mfma_f32_16x16x32_bf16(kf[nf * 2 + s], qb[s], SF[nf], 0, 0, 0);
        __builtin_amdgcn_s_setprio(0);
    };

    // finish phase: softmax + in-register P exchange + PV of tile jv
    auto finPhase = [&](int jv, f32x4 (&SF)[4], int vb) {
        bf16x8 vf[8];
#pragma unroll
        for (int nf = 0; nf < 4; nf++)
#pragma unroll
            for (int s = 0; s < 2; s++)
                vf[nf * 2 + s] = *(const bf16x8*)&Vl[vb][SWZ(nf * 16 + col, s * 4 + g)];
        if (jv == qt) {                                 // causal mask (diag only)
#pragma unroll
            for (int nf = 0; nf < 4; nf++)
#pragma unroll
                for (int r = 0; r < 4; r++)
                    if (jv * 64 + nf * 16 + g * 4 + r > qloc) SF[nf][r] = -3e38f;
        }
        float fm[4];
#pragma unroll
        for (int f = 0; f < 4; f++)
            fm[f] = fmaxf(fmaxf(SF[f][0], SF[f][1]), fmaxf(SF[f][2], SF[f][3]));
        float mt = fmaxf(fmaxf(fm[0], fm[1]), fmaxf(fm[2], fm[3]));
        if (!__all(mt <= mrun + 8.0f)) {                // defer-max (THR=8)
            float mg = fmaxf(mt, __shfl_xor(mt, 16));
            mg = fmaxf(mg, __shfl_xor(mg, 32));
            float mn = fmaxf(mrun, mg);
            float al = exp2f(mrun - mn);
            mrun = mn;
            lsum0 *= al; lsum1 *= al; lsum2 *= al; lsum3 *= al;
#pragma unroll
            for (int nf = 0; nf < 4; nf++) acc[nf] *= al;
        }
#pragma unroll
        for (int f = 0; f < 4; f++) {
            float p0 = exp2f(SF[f][0] - mrun);
            float p1 = exp2f(SF[f][1] - mrun);
            float p2 = exp2f(SF[f][2] - mrun);
            float p3 = exp2f(SF[f][3] - mrun);
            SF[f][0] = p0; SF[f][1] = p1; SF[f][2] = p2; SF[f][3] = p3;
            lsum0 += p0; lsum1 += p1; lsum2 += p2; lsum3 += p3;
        }
        // ---- P^T -> B-fragment fully in-register (verified permlane chain) --
        // lane (g,col) holds P[kv=16nf+4g+r][q=col]; B-frag needs
        // P[kv=32s+8g+i][q=col].  Quarter map: word_lo g=0..3 <- A.q0,A.q2,
        // B.q0,B.q2 (A=d[2s],B=d[2s+1]); word_hi <- A.q1,A.q3,B.q1,B.q3.
        unsigned d0[4], d1[4];
#pragma unroll
        for (int nf = 0; nf < 4; nf++) {
            d0[nf] = pack_bf16(SF[nf][0], SF[nf][1]);
            d1[nf] = pack_bf16(SF[nf][2], SF[nf][3]);
        }
        __builtin_amdgcn_s_setprio(1);
#pragma unroll
        for (int s = 0; s < 2; s++) {
            int2v p0 = __builtin_amdgcn_permlane32_swap((int)d0[2 * s], (int)d0[2 * s + 1], false, false);
            int2v u0 = __builtin_amdgcn_permlane16_swap(p0.x, p0.y, false, false);
            int2v p1 = __builtin_amdgcn_permlane32_swap((int)d1[2 * s], (int)d1[2 * s + 1], false, false);
            int2v u1 = __builtin_amdgcn_permlane16_swap(p1.x, p1.y, false, false);
            uint4v u;
            u.x = (unsigned)u0.x;   // P[+0,+1]  (d0 of g'_low)
            u.y = (unsigned)u1.x;   // P[+2,+3]  (d1 of g'_low)
            u.z = (unsigned)u0.y;   // P[+4,+5]  (d0 of g'_high)
            u.w = (unsigned)u1.y;   // P[+6,+7]  (d1 of g'_high)
            bf16x8 pf = __builtin_bit_cast(bf16x8, u);
#pragma unroll
            for (int nf = 0; nf < 4; nf++)
                acc[nf] = __builtin_amdgcn_mfma_f32_16x16x32_bf16(vf[nf * 2 + s], pf, acc[nf], 0, 0, 0);
        }
        __builtin_amdgcn_s_setprio(0);
    };

    // one pipelined step: QK(jv) into SFq, finish(jv-1) from SFf
    auto iterStep = [&](int jv, f32x4 (&SFq)[4], f32x4 (&SFf)[4], int vb_f) {
        const bool more = (jv + 1 < j1);
        if (more) stageLoad(jv + 1);
        __builtin_amdgcn_sched_barrier(0);
#pragma unroll
        for (int i = 0; i < 4; i++) SFq[i] = 0.f;
        qkPhase(jv, SFq);
        finPhase(jv - 1, SFf, vb_f);
        if (more) {
            stageWriteK((jv + 1) & 1);
            stageWriteV(vb_f + 2 >= 3 ? vb_f - 1 : vb_f + 2);
        }
        __syncthreads();
    };

    // ---- prologue: stage tile j0 ----
    stageLoad(j0);
    stageWriteK(j0 & 1);
    const int vb0 = j0 % 3;                             // 0 for j0=0, 2 for j0=32
    stageWriteV(vb0);
    __syncthreads();

    // ---- iter0: QK(j0) only, stage j0+1 ----
    {
        const bool more = (j0 + 1 < j1);
        if (more) stageLoad(j0 + 1);
        __builtin_amdgcn_sched_barrier(0);
#pragma unroll
        for (int i = 0; i < 4; i++) sfA[i] = 0.f;
        qkPhase(j0, sfA);
        if (more) {
            stageWriteK((j0 + 1) & 1);
            stageWriteV(vb0 + 1 >= 3 ? vb0 - 2 : vb0 + 1);
        }
        __syncthreads();
    }

    int vb_f = vb0;                                     // V buffer of tile j0
    int jv = j0 + 1;
    while (jv + 1 < j1) {
        iterStep(jv, sfB, sfA, vb_f);
        vb_f = (vb_f + 1 >= 3) ? vb_f - 2 : vb_f + 1;
        iterStep(jv + 1, sfA, sfB, vb_f);
        vb_f = (vb_f + 1 >= 3) ? vb_f - 2 : vb_f + 1;
        jv += 2;
    }
    bool lastIsB = false;
    if (jv < j1) {                                      // one leftover step
        iterStep(jv, sfB, sfA, vb_f);
        vb_f = (vb_f + 1 >= 3) ? vb_f - 2 : vb_f + 1;
        lastIsB = true;
    }
    // ---- final finish of tile j1-1 ----
    if (lastIsB) finPhase(j1 - 1, sfB, vb_f);
    else         finPhase(j1 - 1, sfA, vb_f);

    // ---- final l combine across lane-groups ----
    float ls = (lsum0 + lsum1) + (lsum2 + lsum3);
    ls += __shfl_xor(ls, 16);
    ls += __shfl_xor(ls, 32);

    if (!partial) {
        float rinv = __builtin_amdgcn_rcpf(ls);
        float* orow = O + qrow * HS;
#pragma unroll
        for (int nf = 0; nf < 4; nf++) {
            float4 v;
            v.x = acc[nf][0] * rinv; v.y = acc[nf][1] * rinv;
            v.z = acc[nf][2] * rinv; v.w = acc[nf][3] * rinv;
            *(float4*)(orow + nf * 16 + g * 4) = v;
        }
    } else {
        const int slot = (b * 32 + (qt - 32)) * 2 + ch;
        float* prow = Opart + ((size_t)slot * 64 + w * 16 + col) * 64;
#pragma unroll
        for (int nf = 0; nf < 4; nf++) {
            float4 v;
            v.x = acc[nf][0]; v.y = acc[nf][1];
            v.z = acc[nf][2]; v.w = acc[nf][3];
            *(float4*)(prow + nf * 16 + g * 4) = v;
        }
        if (g == 0) {
            float2 mv = make_float2(mrun, ls);
            *(float2*)(mlbuf + ((size_t)slot * 64 + w * 16 + col) * 2) = mv;
        }
    }
#undef SWZ
}

// ---------------------------------------------------------------------------
// Kernel 3: combine the two split-K partials for qt in [32,64).
// ---------------------------------------------------------------------------
__global__ __launch_bounds__(256) void combine_kernel(
    const float* __restrict__ Opart, const float* __restrict__ mlbuf,
    float* __restrict__ O)
{
    const int qi = blockIdx.x;             // 0..31 -> qt = 32+qi
    const int b  = blockIdx.y;
    const int row = threadIdx.x >> 2;
    const int seg = threadIdx.x & 3;
    const int slot0 = (b * 32 + qi) * 2;

    const float* p0 = mlbuf + ((size_t)slot0 * 64 + row) * 2;
    const float* p1 = mlbuf + ((size_t)(slot0 + 1) * 64 + row) * 2;
    float m0 = p0[0], l0 = p0[1];
    float m1 = p1[0], l1 = p1[1];
    float M  = fmaxf(m0, m1);
    float w0 = exp2f(m0 - M), w1 = exp2f(m1 - M);
    float rinv = 1.0f / (l0 * w0 + l1 * w1);
    w0 *= rinv; w1 *= rinv;

    const float4* s0 = (const float4*)(Opart + ((size_t)slot0 * 64 + row) * 64 + seg * 16);
    const float4* s1 = (const float4*)(Opart + ((size_t)(slot0 + 1) * 64 + row) * 64 + seg * 16);
    float4* dst = (float4*)(O + ((size_t)b * TT + (32 + qi) * 64 + row) * 64 + seg * 16);
#pragma unroll
    for (int i = 0; i < 4; i++) {
        float4 a = s0[i], c = s1[i];
        float4 v;
        v.x = a.x * w0 + c.x * w1;
        v.y = a.y * w0 + c.y * w1;
        v.z = a.z * w0 + c.z * w1;
        v.w = a.w * w0 + c.w * w1;
        dst[i] = v;
    }
}

// ---------------------------------------------------------------------------
extern "C" void kernel_launch(void* const* d_in, const int* in_sizes, int n_in,
                              void* d_out, int out_size, void* d_ws, size_t ws_size,
                              hipStream_t stream)
{
    const float* x    = (const float*)d_in[0];
    const float* cosT = (const float*)d_in[1];
    const float* sinT = (const float*)d_in[2];
    const float* Wq   = (const float*)d_in[3];
    const float* Wk   = (const float*)d_in[4];
    const float* Wv   = (const float*)d_in[5];
    float* out = (float*)d_out;

    __bf16* Qb = (__bf16*)d_ws;
    __bf16* Kb = Qb + (size_t)BB * TT * HS;
    __bf16* Vb = Kb + (size_t)BB * TT * HS;   // transposed: [b*64+d][t]
    __bf16* Wt = Vb + (size_t)BB * TT * HS;

    const size_t base_bytes = (size_t)3 * BB * TT * HS * 2 + 192 * 1024 * 2;
    float* Opart = (float*)((char*)d_ws + ((base_bytes + 255) & ~(size_t)255));
    float* mlbuf = Opart + (size_t)8 * 32 * 2 * 64 * 64;   // 8.4 MB of partials

    wprep_kernel<<<(192 * 1024) / 256, 256, 0, stream>>>(Wq, Wk, Wv, Wt);
    qkv_rope_kernel<<<(BB * TT) / 64, 256, 0, stream>>>(x, cosT, sinT, Wt, Qb, Kb, Vb);
    attn_kernel<<<768, 256, 0, stream>>>(Qb, Kb, Vb, out, Opart, mlbuf);
    combine_kernel<<<dim3(32, 8), 256, 0, stream>>>(Opart, mlbuf, out);
}